// Round 3
// baseline (142.972 us; speedup 1.0000x reference)
//
#include <hip/hip_runtime.h>
#include <math.h>

#define QSCALE (0.2886751345948129f * 1.4426950408889634f)  // 1/sqrt(12) * log2(e)

#if __has_builtin(__builtin_amdgcn_exp2f)
#define EXP2F(x) __builtin_amdgcn_exp2f(x)
#else
#define EXP2F(x) exp2f(x)
#endif

typedef __attribute__((ext_vector_type(8))) short bf16x8;
typedef __attribute__((ext_vector_type(4))) float floatx4;
typedef __attribute__((ext_vector_type(4))) unsigned int uintx4;

#define MFMA16(a, b, c) __builtin_amdgcn_mfma_f32_16x16x32_bf16((a), (b), (c), 0, 0, 0)

// ---------------- Kernel A: weight swizzle into MFMA B-fragment order ------
// W[768][12] (q scaled) -> hi/lo bf16 frags. Slot s = (ks*3+nt)*2+sp holds
// 64 lanes * 8 bf16 (16B/lane). B[k][n]: lane = (kq<<4)|n, elems j: k=ks*32+kq*8+j.
__global__ __launch_bounds__(256)
void wswz(const float* __restrict__ Wq, const float* __restrict__ Wk,
          const float* __restrict__ Wv, unsigned short* __restrict__ wsw)
{
    int t = blockIdx.x * 256 + threadIdx.x;
    if (t >= 4608) return;                 // 24 ks * 3 nt * 64 lanes
    int lane = t & 63;
    int nt   = (t >> 6) % 3;
    int ks   = t / 192;
    const float* W = (nt == 0) ? Wq : (nt == 1) ? Wk : Wv;
    const float scale = (nt == 0) ? QSCALE : 1.0f;
    int c  = lane & 15;
    int q8 = lane >> 4;
    uintx4 hi, lo;
    unsigned hv[4], lv[4];
    #pragma unroll
    for (int p = 0; p < 4; ++p) {
        float f0 = 0.f, f1 = 0.f;
        if (c < 12) {
            int k = ks * 32 + q8 * 8 + 2 * p;
            f0 = W[k * 12 + c] * scale;
            f1 = W[(k + 1) * 12 + c] * scale;
        }
        unsigned u0 = __float_as_uint(f0), u1 = __float_as_uint(f1);
        hv[p] = (u0 >> 16) | (u1 & 0xFFFF0000u);
        float r0 = f0 - __uint_as_float(u0 & 0xFFFF0000u);
        float r1 = f1 - __uint_as_float(u1 & 0xFFFF0000u);
        lv[p] = (__float_as_uint(r0) >> 16) | (__float_as_uint(r1) & 0xFFFF0000u);
    }
    hi.x = hv[0]; hi.y = hv[1]; hi.z = hv[2]; hi.w = hv[3];
    lo.x = lv[0]; lo.y = lv[1]; lo.z = lv[2]; lo.w = lv[3];
    char* base = (char*)wsw + (size_t)((ks * 3 + nt) * 2) * 1024 + (size_t)lane * 16;
    *(uintx4*)(base)        = hi;
    *(uintx4*)(base + 1024) = lo;
}

// ---------------- Kernel 0: mask scan / compaction indices ----------------
__global__ __launch_bounds__(256)
void mask_scan(const int* __restrict__ mask, int* __restrict__ dst,
               int* __restrict__ nvalid)
{
    __shared__ int cnt[256];
    const int b = blockIdx.x;
    const int t = threadIdx.x;
    const int* mb = mask + b * 2048;
    int local[8]; int c = 0;
    #pragma unroll
    for (int i = 0; i < 8; ++i) { local[i] = (mb[t * 8 + i] != 0); c += local[i]; }
    cnt[t] = c;
    __syncthreads();
    for (int off = 1; off < 256; off <<= 1) {
        int u = cnt[t];
        int add = (t >= off) ? cnt[t - off] : 0;
        __syncthreads();
        cnt[t] = u + add;
        __syncthreads();
    }
    int run = (t == 0) ? 0 : cnt[t - 1];
    int* db = dst + b * 2048;
    #pragma unroll
    for (int i = 0; i < 8; ++i) { db[t * 8 + i] = local[i] ? run : -1; run += local[i]; }
    if (t == 255) nvalid[b] = cnt[255];
}

// ---------------- Kernel 1: QKV projection as split-bf16 MFMA GEMM ---------
// grid=1024 (16 rows/block), block=256 (4 waves split K 4x192 = 6 K-steps).
// A (x) global->regs->hi/lo bf16; B frags coalesced from wsw (L2-broadcast).
// 9 MFMA per K-step (3 N-tiles x {hh, hl, lh}). LDS cross-wave combine.
__global__ __launch_bounds__(256, 4)
void qkv_mfma(const float* __restrict__ x, const unsigned short* __restrict__ wsw,
              const int* __restrict__ dst, float* __restrict__ q_ws,
              float* __restrict__ kc, float* __restrict__ vc)
{
    __shared__ __align__(16) float cbuf[3072];   // [w][nt][lane][4]
    const int tid  = threadIdx.x;
    const int lane = tid & 63;
    const int w    = tid >> 6;
    const int rowbase = blockIdx.x * 16;
    const int m  = lane & 15;
    const int q8 = lane >> 4;

    const float* xrow = x + (size_t)(rowbase + m) * 768 + q8 * 8;
    const uintx4* wp = (const uintx4*)wsw;   // 16B frag units: idx = slot*64+lane

    floatx4 acc0 = {0.f, 0.f, 0.f, 0.f};
    floatx4 acc1 = acc0, acc2 = acc0;

    int ks0 = w * 6;
    floatx4 xa = *(const floatx4*)(xrow + ks0 * 32);
    floatx4 xb = *(const floatx4*)(xrow + ks0 * 32 + 4);
    uintx4 b0h = wp[((ks0 * 3 + 0) * 2 + 0) * 64 + lane];
    uintx4 b0l = wp[((ks0 * 3 + 0) * 2 + 1) * 64 + lane];
    uintx4 b1h = wp[((ks0 * 3 + 1) * 2 + 0) * 64 + lane];
    uintx4 b1l = wp[((ks0 * 3 + 1) * 2 + 1) * 64 + lane];
    uintx4 b2h = wp[((ks0 * 3 + 2) * 2 + 0) * 64 + lane];
    uintx4 b2l = wp[((ks0 * 3 + 2) * 2 + 1) * 64 + lane];

    #pragma unroll
    for (int s = 0; s < 6; ++s) {
        floatx4 cxa = xa, cxb = xb;
        uintx4 cb0h = b0h, cb0l = b0l, cb1h = b1h, cb1l = b1l, cb2h = b2h, cb2l = b2l;
        if (s < 5) {                      // prefetch next K-step
            int ksn = w * 6 + s + 1;
            xa = *(const floatx4*)(xrow + ksn * 32);
            xb = *(const floatx4*)(xrow + ksn * 32 + 4);
            b0h = wp[((ksn * 3 + 0) * 2 + 0) * 64 + lane];
            b0l = wp[((ksn * 3 + 0) * 2 + 1) * 64 + lane];
            b1h = wp[((ksn * 3 + 1) * 2 + 0) * 64 + lane];
            b1l = wp[((ksn * 3 + 1) * 2 + 1) * 64 + lane];
            b2h = wp[((ksn * 3 + 2) * 2 + 0) * 64 + lane];
            b2l = wp[((ksn * 3 + 2) * 2 + 1) * 64 + lane];
        }
        // split fp32 -> hi/lo bf16 (truncation; residual carries next 8 bits)
        uintx4 ah, al;
        {
            unsigned u0, u1; float r0, r1;
            u0 = __float_as_uint(cxa.x); u1 = __float_as_uint(cxa.y);
            ah.x = (u0 >> 16) | (u1 & 0xFFFF0000u);
            r0 = cxa.x - __uint_as_float(u0 & 0xFFFF0000u);
            r1 = cxa.y - __uint_as_float(u1 & 0xFFFF0000u);
            al.x = (__float_as_uint(r0) >> 16) | (__float_as_uint(r1) & 0xFFFF0000u);
            u0 = __float_as_uint(cxa.z); u1 = __float_as_uint(cxa.w);
            ah.y = (u0 >> 16) | (u1 & 0xFFFF0000u);
            r0 = cxa.z - __uint_as_float(u0 & 0xFFFF0000u);
            r1 = cxa.w - __uint_as_float(u1 & 0xFFFF0000u);
            al.y = (__float_as_uint(r0) >> 16) | (__float_as_uint(r1) & 0xFFFF0000u);
            u0 = __float_as_uint(cxb.x); u1 = __float_as_uint(cxb.y);
            ah.z = (u0 >> 16) | (u1 & 0xFFFF0000u);
            r0 = cxb.x - __uint_as_float(u0 & 0xFFFF0000u);
            r1 = cxb.y - __uint_as_float(u1 & 0xFFFF0000u);
            al.z = (__float_as_uint(r0) >> 16) | (__float_as_uint(r1) & 0xFFFF0000u);
            u0 = __float_as_uint(cxb.z); u1 = __float_as_uint(cxb.w);
            ah.w = (u0 >> 16) | (u1 & 0xFFFF0000u);
            r0 = cxb.z - __uint_as_float(u0 & 0xFFFF0000u);
            r1 = cxb.w - __uint_as_float(u1 & 0xFFFF0000u);
            al.w = (__float_as_uint(r0) >> 16) | (__float_as_uint(r1) & 0xFFFF0000u);
        }
        bf16x8 Ahi = __builtin_bit_cast(bf16x8, ah);
        bf16x8 Alo = __builtin_bit_cast(bf16x8, al);
        acc0 = MFMA16(Ahi, __builtin_bit_cast(bf16x8, cb0h), acc0);
        acc1 = MFMA16(Ahi, __builtin_bit_cast(bf16x8, cb1h), acc1);
        acc2 = MFMA16(Ahi, __builtin_bit_cast(bf16x8, cb2h), acc2);
        acc0 = MFMA16(Alo, __builtin_bit_cast(bf16x8, cb0h), acc0);
        acc1 = MFMA16(Alo, __builtin_bit_cast(bf16x8, cb1h), acc1);
        acc2 = MFMA16(Alo, __builtin_bit_cast(bf16x8, cb2h), acc2);
        acc0 = MFMA16(Ahi, __builtin_bit_cast(bf16x8, cb0l), acc0);
        acc1 = MFMA16(Ahi, __builtin_bit_cast(bf16x8, cb1l), acc1);
        acc2 = MFMA16(Ahi, __builtin_bit_cast(bf16x8, cb2l), acc2);
    }

    *(floatx4*)(cbuf + ((w * 3 + 0) * 64 + lane) * 4) = acc0;
    *(floatx4*)(cbuf + ((w * 3 + 1) * 64 + lane) * 4) = acc1;
    *(floatx4*)(cbuf + ((w * 3 + 2) * 64 + lane) * 4) = acc2;
    __syncthreads();
    if (w < 3) {
        floatx4 t0 = *(const floatx4*)(cbuf + ((0 * 3 + w) * 64 + lane) * 4);
        floatx4 t1 = *(const floatx4*)(cbuf + ((1 * 3 + w) * 64 + lane) * 4);
        floatx4 t2 = *(const floatx4*)(cbuf + ((2 * 3 + w) * 64 + lane) * 4);
        floatx4 t3 = *(const floatx4*)(cbuf + ((3 * 3 + w) * 64 + lane) * 4);
        floatx4 tot = t0 + t1 + t2 + t3;
        const int col = lane & 15;
        if (col < 12) {
            #pragma unroll
            for (int r = 0; r < 4; ++r) {
                const int row = rowbase + (lane >> 4) * 4 + r;
                const float val = tot[r];
                if (w == 0) {
                    q_ws[row * 12 + col] = val;
                } else {
                    const int d = dst[row];
                    if (d >= 0) {
                        const int b = row >> 11;
                        float* o = (w == 1) ? kc : vc;
                        o[(b * 2048 + d) * 12 + col] = val;
                    }
                }
            }
        }
    }
}

// ---------------- Kernel 2: flash attention over compacted keys ------------
// grid=256, block=1024 (16 waves). 512-key LDS tiles, single-buffered with
// register prefetch (4 barriers for nv~1024). Per wave: 32 keys/tile as two
// 16-key two-pass batches in exp2 domain. 16-way LDS combine.
__global__ __launch_bounds__(1024)
void attn(const float* __restrict__ q_ws, const float* __restrict__ kc,
          const float* __restrict__ vc, const int* __restrict__ nvalid_arr,
          float* __restrict__ out)
{
    __shared__ __align__(16) float smem[14336];  // kt[6144] vt[6144]; combine aliases
    const int tid  = threadIdx.x;
    const int lane = tid & 63;
    const int w    = __builtin_amdgcn_readfirstlane(tid >> 6);
    const int bb   = blockIdx.x >> 5;
    const int rg   = blockIdx.x & 31;
    const int row  = bb * 2048 + rg * 64 + lane;

    float q[12];
    {
        const floatx4* qp = (const floatx4*)(q_ws + (size_t)row * 12);
        floatx4 a = qp[0], b = qp[1], c = qp[2];
        q[0]=a.x; q[1]=a.y; q[2]=a.z;  q[3]=a.w;
        q[4]=b.x; q[5]=b.y; q[6]=b.z;  q[7]=b.w;
        q[8]=c.x; q[9]=c.y; q[10]=c.z; q[11]=c.w;
    }

    const float* kb = kc + (size_t)bb * 24576;
    const float* vb = vc + (size_t)bb * 24576;
    const int nv    = nvalid_arr[bb];
    const int ntile = (nv + 511) >> 9;

    #pragma unroll
    for (int j = 0; j < 6; ++j) {        // stage tile 0 (512 keys)
        int idx = tid + j * 1024;
        smem[idx]        = kb[idx];
        smem[6144 + idx] = vb[idx];
    }
    __syncthreads();

    float m = -INFINITY, l = 0.f;
    float o[12];
    #pragma unroll
    for (int j = 0; j < 12; ++j) o[j] = 0.f;

    for (int t = 0; t < ntile; ++t) {
        float pk[6], pv[6];
        const bool havenext = (t + 1 < ntile);
        if (havenext) {
            const int off = (t + 1) * 6144;
            #pragma unroll
            for (int j = 0; j < 6; ++j) {
                pk[j] = kb[off + tid + j * 1024];
                pv[j] = vb[off + tid + j * 1024];
            }
        }
        #pragma unroll
        for (int h = 0; h < 2; ++h) {
            const int kl    = w * 32 + h * 16;       // local key base in tile
            const int kbase = t * 512 + kl;          // global compacted key base
            float s[16];
            float mnew = m;
            #pragma unroll
            for (int i = 0; i < 16; ++i) {
                const floatx4* kr = (const floatx4*)(smem + (kl + i) * 12);
                floatx4 a = kr[0], b = kr[1], c = kr[2];
                float t0 = q[0] * a.x, t1 = q[1] * a.y, t2 = q[2] * a.z, t3 = q[3] * a.w;
                t0 = fmaf(q[4], b.x, t0); t1 = fmaf(q[5], b.y, t1);
                t2 = fmaf(q[6], b.z, t2); t3 = fmaf(q[7], b.w, t3);
                t0 = fmaf(q[8], c.x, t0); t1 = fmaf(q[9], c.y, t1);
                t2 = fmaf(q[10], c.z, t2); t3 = fmaf(q[11], c.w, t3);
                float sv = (t0 + t1) + (t2 + t3);
                s[i] = (kbase + i < nv) ? sv : -INFINITY;
                mnew = fmaxf(mnew, s[i]);
            }
            float corr = (m < mnew) ? EXP2F(m - mnew) : 1.0f;
            l *= corr;
            #pragma unroll
            for (int j = 0; j < 12; ++j) o[j] *= corr;
            if (mnew > -INFINITY) {
                #pragma unroll
                for (int i = 0; i < 16; ++i) {
                    float p = EXP2F(s[i] - mnew);
                    l += p;
                    const floatx4* vr = (const floatx4*)(smem + 6144 + (kl + i) * 12);
                    floatx4 a = vr[0], b = vr[1], c = vr[2];
                    o[0] = fmaf(p, a.x, o[0]);   o[1] = fmaf(p, a.y, o[1]);
                    o[2] = fmaf(p, a.z, o[2]);   o[3] = fmaf(p, a.w, o[3]);
                    o[4] = fmaf(p, b.x, o[4]);   o[5] = fmaf(p, b.y, o[5]);
                    o[6] = fmaf(p, b.z, o[6]);   o[7] = fmaf(p, b.w, o[7]);
                    o[8] = fmaf(p, c.x, o[8]);   o[9] = fmaf(p, c.y, o[9]);
                    o[10] = fmaf(p, c.z, o[10]); o[11] = fmaf(p, c.w, o[11]);
                }
            }
            m = mnew;
        }
        if (havenext) {
            __syncthreads();
            #pragma unroll
            for (int j = 0; j < 6; ++j) {
                smem[tid + j * 1024]        = pk[j];
                smem[6144 + tid + j * 1024] = pv[j];
            }
            __syncthreads();
        }
    }

    __syncthreads();   // everyone done computing before aliasing tile region
    float* cm = smem;          // 16*64
    float* cl = smem + 1024;   // 16*64
    float* co = smem + 2048;   // 16*64*12
    cm[w * 64 + lane] = m;
    cl[w * 64 + lane] = l;
    {
        float* p = co + (w * 64 + lane) * 12;
        #pragma unroll
        for (int j = 0; j < 12; ++j) p[j] = o[j];
    }
    __syncthreads();
    if (tid < 64) {
        float gm = -INFINITY;
        #pragma unroll
        for (int w2 = 0; w2 < 16; ++w2) gm = fmaxf(gm, cm[w2 * 64 + tid]);
        float L = 0.f;
        float O[12];
        #pragma unroll
        for (int j = 0; j < 12; ++j) O[j] = 0.f;
        #pragma unroll
        for (int w2 = 0; w2 < 16; ++w2) {
            float a = EXP2F(cm[w2 * 64 + tid] - gm);
            L = fmaf(cl[w2 * 64 + tid], a, L);
            const float* p = co + (w2 * 64 + tid) * 12;
            #pragma unroll
            for (int j = 0; j < 12; ++j) O[j] = fmaf(p[j], a, O[j]);
        }
        const float inv = 1.f / L;
        floatx4* op = (floatx4*)(out + (size_t)(bb * 2048 + rg * 64 + tid) * 12);
        floatx4 o0, o1, o2;
        o0.x = O[0]*inv;  o0.y = O[1]*inv;  o0.z = O[2]*inv;  o0.w = O[3]*inv;
        o1.x = O[4]*inv;  o1.y = O[5]*inv;  o1.z = O[6]*inv;  o1.w = O[7]*inv;
        o2.x = O[8]*inv;  o2.y = O[9]*inv;  o2.z = O[10]*inv; o2.w = O[11]*inv;
        op[0] = o0; op[1] = o1; op[2] = o2;
    }
}

extern "C" void kernel_launch(void* const* d_in, const int* in_sizes, int n_in,
                              void* d_out, int out_size, void* d_ws, size_t ws_size,
                              hipStream_t stream) {
    const float* x    = (const float*)d_in[0];
    const int*   mask = (const int*)  d_in[1];
    const float* Wk   = (const float*)d_in[2];   // key_weight
    const float* Wq   = (const float*)d_in[3];   // query_weight
    const float* Wv   = (const float*)d_in[4];   // value_weight
    float* out = (float*)d_out;

    float* ws     = (float*)d_ws;
    float* q_ws   = ws;                               // 196608 floats
    float* kc     = ws + 196608;                      // 196608 floats (compacted)
    float* vc     = ws + 393216;                      // 196608 floats (compacted)
    int*   dst    = (int*)(ws + 589824);              // 16384 ints
    int*   nvalid = (int*)(ws + 589824 + 16384);      // 8 ints
    unsigned short* wsw = (unsigned short*)(ws + 606216);  // 73728 ushorts (16B-aligned)

    wswz<<<18, 256, 0, stream>>>(Wq, Wk, Wv, wsw);
    mask_scan<<<8, 256, 0, stream>>>(mask, dst, nvalid);
    qkv_mfma<<<1024, 256, 0, stream>>>(x, wsw, dst, q_ws, kc, vc);
    attn<<<256, 1024, 0, stream>>>(q_ws, kc, vc, nvalid, out);
}

// Round 4
// 115.201 us; speedup vs baseline: 1.2411x; 1.2411x over previous
//
#include <hip/hip_runtime.h>
#include <math.h>

#define QSCALE (0.2886751345948129f * 1.4426950408889634f)  // 1/sqrt(12) * log2(e)

#if __has_builtin(__builtin_amdgcn_exp2f)
#define EXP2F(x) __builtin_amdgcn_exp2f(x)
#else
#define EXP2F(x) exp2f(x)
#endif

typedef __attribute__((ext_vector_type(8))) _Float16 half8;
typedef __attribute__((ext_vector_type(4))) _Float16 half4_t;
typedef __attribute__((ext_vector_type(4))) float floatx4;

#define MFMA32F16(a, b, c) __builtin_amdgcn_mfma_f32_16x16x32_f16((a), (b), (c), 0, 0, 0)
#define MFMA16F16(a, b, c) __builtin_amdgcn_mfma_f32_16x16x16f16((a), (b), (c), 0, 0, 0)

static __device__ inline float bperm(float v, int addr_bytes) {
    return __int_as_float(__builtin_amdgcn_ds_bpermute(addr_bytes, __float_as_int(v)));
}

// ---------------- Kernel A: weight swizzle -> fp16 hi/lo B-fragments -------
// Slot (ks,nt): B[k=dim q8*8+j][n=col]; lane = q8*16+col; 8 fp16 per lane.
__global__ __launch_bounds__(256)
void wswz(const float* __restrict__ Wq, const float* __restrict__ Wk,
          const float* __restrict__ Wv, _Float16* __restrict__ wfh,
          _Float16* __restrict__ wfl)
{
    int t = blockIdx.x * 256 + threadIdx.x;
    if (t >= 4608) return;                 // 24 ks * 3 nt * 64 lanes
    int lane = t & 63;
    int nt   = (t >> 6) % 3;
    int ks   = t / 192;
    const float* W = (nt == 0) ? Wq : (nt == 1) ? Wk : Wv;
    const float scale = (nt == 0) ? QSCALE : 1.0f;
    int col = lane & 15;
    int q8  = lane >> 4;
    half8 hi, lo;
    #pragma unroll
    for (int j = 0; j < 8; ++j) {
        int dim = ks * 32 + q8 * 8 + j;    // < 768 always
        float f = (col < 12) ? W[dim * 12 + col] * scale : 0.0f;
        _Float16 h = (_Float16)f;
        hi[j] = h;
        lo[j] = (_Float16)(f - (float)h);
    }
    size_t off = ((size_t)(ks * 3 + nt) * 64 + lane) * 8;
    *(half8*)(wfh + off) = hi;
    *(half8*)(wfl + off) = lo;
}

// ---------------- Kernel 0: mask scan / compaction indices ----------------
__global__ __launch_bounds__(256)
void mask_scan(const int* __restrict__ mask, int* __restrict__ dst,
               int* __restrict__ nvalid)
{
    __shared__ int cnt[256];
    const int b = blockIdx.x;
    const int t = threadIdx.x;
    const int* mb = mask + b * 2048;
    int local[8]; int c = 0;
    #pragma unroll
    for (int i = 0; i < 8; ++i) { local[i] = (mb[t * 8 + i] != 0); c += local[i]; }
    cnt[t] = c;
    __syncthreads();
    for (int off = 1; off < 256; off <<= 1) {
        int u = cnt[t];
        int add = (t >= off) ? cnt[t - off] : 0;
        __syncthreads();
        cnt[t] = u + add;
        __syncthreads();
    }
    int run = (t == 0) ? 0 : cnt[t - 1];
    int* db = dst + b * 2048;
    #pragma unroll
    for (int i = 0; i < 8; ++i) { db[t * 8 + i] = local[i] ? run : -1; run += local[i]; }
    if (t == 255) nvalid[b] = cnt[255];
}

// ---------------- Kernel Z: zero the fragment workspace -------------------
__global__ __launch_bounds__(256)
void zero_frag(float4* __restrict__ p, int n)
{
    int i = blockIdx.x * 256 + threadIdx.x;
    float4 z = make_float4(0.f, 0.f, 0.f, 0.f);
    if (i < n) p[i] = z;
}

// ---------------- Kernel 1: QKV projection, fp16-split MFMA ----------------
// grid=1024 (16 rows), block=256 (4 waves split K: 6 x 32-dim steps each).
// x staged to LDS in one 48KB burst (full MLP); W frags from L2. Epilogue
// writes q/k/v straight into attention fragment layouts (fp16 hi/lo).
__global__ __launch_bounds__(256, 2)
void qkv_mfma(const float* __restrict__ x, const _Float16* __restrict__ wfh,
              const _Float16* __restrict__ wfl, const int* __restrict__ dst,
              _Float16* __restrict__ qfh, _Float16* __restrict__ qfl,
              _Float16* __restrict__ kfh, _Float16* __restrict__ kfl,
              _Float16* __restrict__ vtf)
{
    __shared__ float xs[12352];            // 16 rows * 772 (pad) ; aliased as cbuf
    const int tid  = threadIdx.x;
    const int lane = tid & 63;
    const int w    = tid >> 6;
    const int g    = blockIdx.x;
    const int rowbase = g * 16;

    // ---- stage x tile (coalesced, all loads in flight at once) ----
    {
        const int r  = tid >> 4;
        const int c0 = (tid & 15) * 4;
        const float* xr = x + (size_t)(rowbase + r) * 768 + c0;
        float* xd = xs + r * 772 + c0;
        #pragma unroll
        for (int i = 0; i < 12; ++i) {
            float4 v = *(const float4*)(xr + i * 64);
            *(float4*)(xd + i * 64) = v;
        }
    }
    __syncthreads();

    floatx4 acc0 = {0.f, 0.f, 0.f, 0.f};
    floatx4 acc1 = acc0, acc2 = acc0;
    const int m15 = lane & 15;
    const int q8  = lane >> 4;
    const float* xsrc = xs + m15 * 772 + q8 * 8;
    const half8* WH = (const half8*)wfh;
    const half8* WL = (const half8*)wfl;

    #pragma unroll
    for (int s6 = 0; s6 < 6; ++s6) {
        const int ks = w * 6 + s6;
        float xv[8];
        *(float4*)(xv)     = *(const float4*)(xsrc + ks * 32);
        *(float4*)(xv + 4) = *(const float4*)(xsrc + ks * 32 + 4);
        half8 ah, al;
        #pragma unroll
        for (int j = 0; j < 8; ++j) {
            _Float16 h = (_Float16)xv[j];
            ah[j] = h;
            al[j] = (_Float16)(xv[j] - (float)h);
        }
        half8 b0h = WH[(ks * 3 + 0) * 64 + lane];
        half8 b1h = WH[(ks * 3 + 1) * 64 + lane];
        half8 b2h = WH[(ks * 3 + 2) * 64 + lane];
        half8 b0l = WL[(ks * 3 + 0) * 64 + lane];
        half8 b1l = WL[(ks * 3 + 1) * 64 + lane];
        half8 b2l = WL[(ks * 3 + 2) * 64 + lane];
        acc0 = MFMA32F16(ah, b0h, acc0);
        acc1 = MFMA32F16(ah, b1h, acc1);
        acc2 = MFMA32F16(ah, b2h, acc2);
        acc0 = MFMA32F16(al, b0h, acc0);
        acc1 = MFMA32F16(al, b1h, acc1);
        acc2 = MFMA32F16(al, b2h, acc2);
        acc0 = MFMA32F16(ah, b0l, acc0);
        acc1 = MFMA32F16(ah, b1l, acc1);
        acc2 = MFMA32F16(ah, b2l, acc2);
    }

    __syncthreads();                       // done reading xs; reuse as cbuf
    float* cbuf = xs;
    *(floatx4*)(cbuf + ((w * 3 + 0) * 64 + lane) * 4) = acc0;
    *(floatx4*)(cbuf + ((w * 3 + 1) * 64 + lane) * 4) = acc1;
    *(floatx4*)(cbuf + ((w * 3 + 2) * 64 + lane) * 4) = acc2;
    __syncthreads();
    if (w < 3) {
        floatx4 t0 = *(const floatx4*)(cbuf + ((0 * 3 + w) * 64 + lane) * 4);
        floatx4 t1 = *(const floatx4*)(cbuf + ((1 * 3 + w) * 64 + lane) * 4);
        floatx4 t2 = *(const floatx4*)(cbuf + ((2 * 3 + w) * 64 + lane) * 4);
        floatx4 t3 = *(const floatx4*)(cbuf + ((3 * 3 + w) * 64 + lane) * 4);
        floatx4 tot = t0 + t1 + t2 + t3;
        const int col = m15;               // output head-dim (or col index)
        const int r0  = q8 * 4;            // C-layout rows
        #pragma unroll
        for (int r = 0; r < 4; ++r) {
            const int row = rowbase + r0 + r;
            const float val = tot[r];
            if (w == 0) {                  // Q -> B-frag layout, hi/lo
                if (col < 12) {
                    size_t off = ((size_t)g * 64 + (col >> 3) * 16 + (r0 + r)) * 8 + (col & 7);
                    _Float16 h = (_Float16)val;
                    qfh[off] = h;
                    qfl[off] = (_Float16)(val - (float)h);
                }
            } else {
                const int d = dst[row];
                if (d >= 0) {
                    const int bb = row >> 11;
                    if (w == 1) {          // K -> A-frag layout, hi/lo (compacted)
                        if (col < 12) {
                            size_t off = (((size_t)(bb * 128 + (d >> 4))) * 64
                                          + (col >> 3) * 16 + (d & 15)) * 8 + (col & 7);
                            _Float16 h = (_Float16)val;
                            kfh[off] = h;
                            kfl[off] = (_Float16)(val - (float)h);
                        }
                    } else {               // V^T -> A-frag layout (fp16), + ones row
                        if (col < 12) {
                            size_t off = (((size_t)(bb * 128 + (d >> 4))) * 64
                                          + ((d & 15) >> 2) * 16 + col) * 4 + (d & 3);
                            vtf[off] = (_Float16)val;
                        } else if (col == 12) {   // l-accumulator ones row
                            size_t off = (((size_t)(bb * 128 + (d >> 4))) * 64
                                          + ((d & 15) >> 2) * 16 + 12) * 4 + (d & 3);
                            vtf[off] = (_Float16)1.0f;
                        }
                    }
                }
            }
        }
    }
}

// ---------------- Kernel 2: MFMA flash attention ---------------------------
// grid=1024 (one 16-row q-group per block), block=256 (4 waves split keys,
// stride-4 over 16-key tiles). S^T = K*Q^T (16x16x32_f16, k-dim = h = 12/32);
// row-max via 2 bpermutes; PV^T via 16x16x16f16 whose B-frag (4 keys/lane)
// matches S^T's C-layout exactly; l accumulated by the ones row at h=12.
// Padding keys are self-masking (k=0 -> s=0, v=ones=0).
__global__ __launch_bounds__(256)
void attn(const _Float16* __restrict__ qfh, const _Float16* __restrict__ qfl,
          const _Float16* __restrict__ kfh, const _Float16* __restrict__ kfl,
          const _Float16* __restrict__ vtf, const int* __restrict__ nvalid,
          float* __restrict__ out)
{
    __shared__ float cm[256];
    __shared__ __align__(16) floatx4 co[256];
    const int tid  = threadIdx.x;
    const int lane = tid & 63;
    const int w    = tid >> 6;
    const int g    = blockIdx.x;           // q row-group (16 rows)
    const int bb   = g >> 7;               // batch (128 groups/batch)
    const int m15  = lane & 15;

    const half8 qh = *(const half8*)(qfh + ((size_t)g * 64 + lane) * 8);
    const half8 ql = *(const half8*)(qfl + ((size_t)g * 64 + lane) * 8);

    const half8* KH = (const half8*)kfh + (size_t)bb * 128 * 64;
    const half8* KL = (const half8*)kfl + (size_t)bb * 128 * 64;
    const half4_t* VT = (const half4_t*)vtf + (size_t)bb * 128 * 64;

    const int nv = nvalid[bb];
    const int nt = (nv + 15) >> 4;         // 16-key tiles (<=128)
    const int a16 = (lane ^ 16) << 2;
    const int a32 = (lane ^ 32) << 2;

    float mrow = -INFINITY;
    floatx4 o = {0.f, 0.f, 0.f, 0.f};

    int t = w;
    half8 kh, kl;
    half4_t va;
    if (t < nt) {
        kh = KH[t * 64 + lane];
        kl = KL[t * 64 + lane];
        va = VT[t * 64 + lane];
    }
    for (; t < nt; t += 4) {
        half8 nkh, nkl; half4_t nva;
        if (t + 4 < nt) {                  // prefetch next tile
            nkh = KH[(t + 4) * 64 + lane];
            nkl = KL[(t + 4) * 64 + lane];
            nva = VT[(t + 4) * 64 + lane];
        }
        floatx4 s = {0.f, 0.f, 0.f, 0.f};
        s = MFMA32F16(kh, qh, s);
        s = MFMA32F16(kl, qh, s);
        s = MFMA32F16(kh, ql, s);
        // row-max (uniform per q-row across the 4 key-quads)
        float pm = fmaxf(fmaxf(s.x, s.y), fmaxf(s.z, s.w));
        pm = fmaxf(pm, bperm(pm, a16));
        pm = fmaxf(pm, bperm(pm, a32));
        float mnew = fmaxf(mrow, pm);
        float corr = EXP2F(mrow - mnew);
        o.x *= corr; o.y *= corr; o.z *= corr; o.w *= corr;
        half4_t pb;
        pb[0] = (_Float16)EXP2F(s.x - mnew);
        pb[1] = (_Float16)EXP2F(s.y - mnew);
        pb[2] = (_Float16)EXP2F(s.z - mnew);
        pb[3] = (_Float16)EXP2F(s.w - mnew);
        o = MFMA16F16(va, pb, o);
        mrow = mnew;
        kh = nkh; kl = nkl; va = nva;
    }

    // ---- 4-way combine ----
    cm[w * 64 + lane] = mrow;
    co[w * 64 + lane] = o;
    __syncthreads();
    float gm = -INFINITY;
    #pragma unroll
    for (int w2 = 0; w2 < 4; ++w2) gm = fmaxf(gm, cm[w2 * 64 + lane]);
    floatx4 O = {0.f, 0.f, 0.f, 0.f};
    #pragma unroll
    for (int w2 = 0; w2 < 4; ++w2) {
        float f = EXP2F(cm[w2 * 64 + lane] - gm);
        floatx4 ow = co[w2 * 64 + lane];
        O.x += ow.x * f; O.y += ow.y * f; O.z += ow.z * f; O.w += ow.w * f;
    }
    // l lives at C row h=12 -> lane (q8=3, m), reg 0
    float L = bperm(O.x, (48 + m15) << 2);
    float inv = 1.0f / L;
    if (w == 0 && (lane >> 4) < 3) {
        float4 ov = make_float4(O.x * inv, O.y * inv, O.z * inv, O.w * inv);
        *(float4*)(out + ((size_t)g * 16 + m15) * 12 + (lane >> 4) * 4) = ov;
    }
}

extern "C" void kernel_launch(void* const* d_in, const int* in_sizes, int n_in,
                              void* d_out, int out_size, void* d_ws, size_t ws_size,
                              hipStream_t stream) {
    const float* x    = (const float*)d_in[0];
    const int*   mask = (const int*)  d_in[1];
    const float* Wk   = (const float*)d_in[2];   // key_weight
    const float* Wq   = (const float*)d_in[3];   // query_weight
    const float* Wv   = (const float*)d_in[4];   // value_weight
    float* out = (float*)d_out;

    char* base = (char*)d_ws;
    _Float16* qfh = (_Float16*)(base);                    // 1 MB
    _Float16* qfl = (_Float16*)(base + (1u << 20));       // 1 MB
    _Float16* kfh = (_Float16*)(base + (2u << 20));       // 1 MB
    _Float16* kfl = (_Float16*)(base + (3u << 20));       // 1 MB
    _Float16* vtf = (_Float16*)(base + (4u << 20));       // 0.5 MB
    // zero region = [0, 4.5 MB)
    _Float16* wfh = (_Float16*)(base + 4718592);          // 73728 B
    _Float16* wfl = (_Float16*)(base + 4718592 + 73728);  // 73728 B
    int* dst      = (int*)(base + 4866048);               // 64 KB
    int* nvalid   = (int*)(base + 4866048 + 65536);       // 32 B

    const int zero_n = 4718592 / 16;                      // float4 count
    wswz<<<18, 256, 0, stream>>>(Wq, Wk, Wv, wfh, wfl);
    mask_scan<<<8, 256, 0, stream>>>(mask, dst, nvalid);
    zero_frag<<<(zero_n + 255) / 256, 256, 0, stream>>>((float4*)base, zero_n);
    qkv_mfma<<<1024, 256, 0, stream>>>(x, wfh, wfl, dst, qfh, qfl, kfh, kfl, vtf);
    attn<<<1024, 256, 0, stream>>>(qfh, qfl, kfh, kfl, vtf, nvalid, out);
}

// Round 5
// 113.331 us; speedup vs baseline: 1.2615x; 1.0165x over previous
//
#include <hip/hip_runtime.h>
#include <math.h>

#define QSCALE (0.2886751345948129f * 1.4426950408889634f)  // 1/sqrt(12) * log2(e)

#if __has_builtin(__builtin_amdgcn_exp2f)
#define EXP2F(x) __builtin_amdgcn_exp2f(x)
#else
#define EXP2F(x) exp2f(x)
#endif

typedef __attribute__((ext_vector_type(8))) _Float16 half8;
typedef __attribute__((ext_vector_type(4))) _Float16 half4_t;
typedef __attribute__((ext_vector_type(4))) float floatx4;

#define MFMA32F16(a, b, c) __builtin_amdgcn_mfma_f32_16x16x32_f16((a), (b), (c), 0, 0, 0)
#define MFMA16F16(a, b, c) __builtin_amdgcn_mfma_f32_16x16x16f16((a), (b), (c), 0, 0, 0)

static __device__ inline float bperm(float v, int addr_bytes) {
    return __int_as_float(__builtin_amdgcn_ds_bpermute(addr_bytes, __float_as_int(v)));
}

// ---------------- Kernel P: fused prep (wswz | mask_scan | zero) -----------
// blocks 0..17: weight swizzle -> fp16 hi/lo B-frags
// blocks 18..25: per-batch mask scan/compaction
// blocks 26..31: zero kfh/kfl/vtf region (2.5 MB). Q frags stay poisoned:
//   0xAA fp16 is finite and multiplies zeroed K-frag k>=12 lanes -> 0.
__global__ __launch_bounds__(256)
void prep(const float* __restrict__ Wq, const float* __restrict__ Wk,
          const float* __restrict__ Wv, const int* __restrict__ mask,
          _Float16* __restrict__ wfh, _Float16* __restrict__ wfl,
          int* __restrict__ dst, int* __restrict__ nvalid,
          float4* __restrict__ zbase)
{
    const int b = blockIdx.x;
    const int tid = threadIdx.x;
    if (b < 18) {
        int t = b * 256 + tid;
        if (t >= 4608) return;             // 24 ks * 3 nt * 64 lanes
        int lane = t & 63;
        int nt   = (t >> 6) % 3;
        int ks   = t / 192;
        const float* W = (nt == 0) ? Wq : (nt == 1) ? Wk : Wv;
        const float scale = (nt == 0) ? QSCALE : 1.0f;
        int col = lane & 15;
        int q8  = lane >> 4;
        half8 hi, lo;
        #pragma unroll
        for (int j = 0; j < 8; ++j) {
            int dim = ks * 32 + q8 * 8 + j;
            float f = (col < 12) ? W[dim * 12 + col] * scale : 0.0f;
            _Float16 h = (_Float16)f;
            hi[j] = h;
            lo[j] = (_Float16)(f - (float)h);
        }
        size_t off = ((size_t)(ks * 3 + nt) * 64 + lane) * 8;
        *(half8*)(wfh + off) = hi;
        *(half8*)(wfl + off) = lo;
    } else if (b < 26) {
        __shared__ int cnt[256];
        const int bb = b - 18;
        const int* mb = mask + bb * 2048;
        int local[8]; int c = 0;
        #pragma unroll
        for (int i = 0; i < 8; ++i) { local[i] = (mb[tid * 8 + i] != 0); c += local[i]; }
        cnt[tid] = c;
        __syncthreads();
        for (int off = 1; off < 256; off <<= 1) {
            int u = cnt[tid];
            int add = (tid >= off) ? cnt[tid - off] : 0;
            __syncthreads();
            cnt[tid] = u + add;
            __syncthreads();
        }
        int run = (tid == 0) ? 0 : cnt[tid - 1];
        int* db = dst + bb * 2048;
        #pragma unroll
        for (int i = 0; i < 8; ++i) { db[tid * 8 + i] = local[i] ? run : -1; run += local[i]; }
        if (tid == 255) nvalid[bb] = cnt[255];
    } else {
        const float4 z = make_float4(0.f, 0.f, 0.f, 0.f);
        for (int i = (b - 26) * 256 + tid; i < 163840; i += 6 * 256) zbase[i] = z;
    }
}

// ---------------- Kernel 1: QKV projection, fp16-split MFMA ----------------
// grid=1024 (16 rows/block), block=256 (4 waves split K: 6 x 32-dim steps).
// A-frags loaded directly from global (xa/xb pair fully consumes each 128B
// line); all 6 steps' x issued up front (12 loads in flight); W frags
// double-buffered from L2. Only LDS use is the 12 KB combine buffer.
__global__ __launch_bounds__(256, 3)
void qkv_mfma(const float* __restrict__ x, const _Float16* __restrict__ wfh,
              const _Float16* __restrict__ wfl, const int* __restrict__ dst,
              _Float16* __restrict__ qfh, _Float16* __restrict__ qfl,
              _Float16* __restrict__ kfh, _Float16* __restrict__ kfl,
              _Float16* __restrict__ vtf)
{
    __shared__ __align__(16) float cbuf[3072];   // [w][nt][lane][4]
    const int tid  = threadIdx.x;
    const int lane = tid & 63;
    const int w    = tid >> 6;
    const int g    = blockIdx.x;
    const int rowbase = g * 16;
    const int m15 = lane & 15;
    const int q8  = lane >> 4;

    const float* xbase = x + (size_t)(rowbase + m15) * 768 + q8 * 8;
    const half8* WH = (const half8*)wfh;
    const half8* WL = (const half8*)wfl;

    // issue ALL x loads up front (independent, 12 in flight)
    float xv[6][8];
    #pragma unroll
    for (int s = 0; s < 6; ++s) {
        const int ks = w * 6 + s;
        *(float4*)(xv[s])     = *(const float4*)(xbase + ks * 32);
        *(float4*)(xv[s] + 4) = *(const float4*)(xbase + ks * 32 + 4);
    }

    floatx4 acc0 = {0.f, 0.f, 0.f, 0.f};
    floatx4 acc1 = acc0, acc2 = acc0;

    // weight frags: double-buffered
    half8 bh[2][3], bl[2][3];
    {
        const int ks = w * 6;
        #pragma unroll
        for (int n = 0; n < 3; ++n) {
            bh[0][n] = WH[(ks * 3 + n) * 64 + lane];
            bl[0][n] = WL[(ks * 3 + n) * 64 + lane];
        }
    }

    #pragma unroll
    for (int s = 0; s < 6; ++s) {
        const int cur = s & 1, nxt = cur ^ 1;
        if (s < 5) {
            const int ksn = w * 6 + s + 1;
            #pragma unroll
            for (int n = 0; n < 3; ++n) {
                bh[nxt][n] = WH[(ksn * 3 + n) * 64 + lane];
                bl[nxt][n] = WL[(ksn * 3 + n) * 64 + lane];
            }
        }
        half8 ah, al;
        #pragma unroll
        for (int j = 0; j < 8; ++j) {
            _Float16 h = (_Float16)xv[s][j];
            ah[j] = h;
            al[j] = (_Float16)(xv[s][j] - (float)h);
        }
        acc0 = MFMA32F16(ah, bh[cur][0], acc0);
        acc1 = MFMA32F16(ah, bh[cur][1], acc1);
        acc2 = MFMA32F16(ah, bh[cur][2], acc2);
        acc0 = MFMA32F16(al, bh[cur][0], acc0);
        acc1 = MFMA32F16(al, bh[cur][1], acc1);
        acc2 = MFMA32F16(al, bh[cur][2], acc2);
        acc0 = MFMA32F16(ah, bl[cur][0], acc0);
        acc1 = MFMA32F16(ah, bl[cur][1], acc1);
        acc2 = MFMA32F16(ah, bl[cur][2], acc2);
    }

    *(floatx4*)(cbuf + ((w * 3 + 0) * 64 + lane) * 4) = acc0;
    *(floatx4*)(cbuf + ((w * 3 + 1) * 64 + lane) * 4) = acc1;
    *(floatx4*)(cbuf + ((w * 3 + 2) * 64 + lane) * 4) = acc2;
    __syncthreads();
    if (w < 3) {
        floatx4 t0 = *(const floatx4*)(cbuf + ((0 * 3 + w) * 64 + lane) * 4);
        floatx4 t1 = *(const floatx4*)(cbuf + ((1 * 3 + w) * 64 + lane) * 4);
        floatx4 t2 = *(const floatx4*)(cbuf + ((2 * 3 + w) * 64 + lane) * 4);
        floatx4 t3 = *(const floatx4*)(cbuf + ((3 * 3 + w) * 64 + lane) * 4);
        floatx4 tot = t0 + t1 + t2 + t3;
        const int col = m15;
        const int r0  = q8 * 4;
        #pragma unroll
        for (int r = 0; r < 4; ++r) {
            const int row = rowbase + r0 + r;
            const float val = tot[r];
            if (w == 0) {                  // Q -> B-frag layout, hi/lo
                if (col < 12) {
                    size_t off = ((size_t)g * 64 + (col >> 3) * 16 + (r0 + r)) * 8 + (col & 7);
                    _Float16 h = (_Float16)val;
                    qfh[off] = h;
                    qfl[off] = (_Float16)(val - (float)h);
                }
            } else {
                const int d = dst[row];
                if (d >= 0) {
                    const int bb = row >> 11;
                    if (w == 1) {          // K -> A-frag layout, hi/lo (compacted)
                        if (col < 12) {
                            size_t off = (((size_t)(bb * 128 + (d >> 4))) * 64
                                          + (col >> 3) * 16 + (d & 15)) * 8 + (col & 7);
                            _Float16 h = (_Float16)val;
                            kfh[off] = h;
                            kfl[off] = (_Float16)(val - (float)h);
                        }
                    } else {               // V^T -> A-frag layout (fp16), + ones row
                        if (col < 12) {
                            size_t off = (((size_t)(bb * 128 + (d >> 4))) * 64
                                          + ((d & 15) >> 2) * 16 + col) * 4 + (d & 3);
                            vtf[off] = (_Float16)val;
                        } else if (col == 12) {   // l-accumulator ones row
                            size_t off = (((size_t)(bb * 128 + (d >> 4))) * 64
                                          + ((d & 15) >> 2) * 16 + 12) * 4 + (d & 3);
                            vtf[off] = (_Float16)1.0f;
                        }
                    }
                }
            }
        }
    }
}

// ---------------- Kernel 2: MFMA flash attention ---------------------------
// grid=512 (two 16-row q-groups per block), block=256 (4 waves stride-4 over
// 16-key tiles). XCD swizzle: batch = blockIdx&7 pins each batch's blocks to
// one XCD (2.8 MB working set < 4 MB L2). Two independent score chains per
// tile (2x MFMA ILP); K/V tile loads amortized over 32 q-rows.
__global__ __launch_bounds__(256)
void attn(const _Float16* __restrict__ qfh, const _Float16* __restrict__ qfl,
          const _Float16* __restrict__ kfh, const _Float16* __restrict__ kfl,
          const _Float16* __restrict__ vtf, const int* __restrict__ nvalid,
          float* __restrict__ out)
{
    __shared__ float cm[512];
    __shared__ __align__(16) floatx4 co[512];
    const int tid  = threadIdx.x;
    const int lane = tid & 63;
    const int w    = tid >> 6;
    const int bb   = blockIdx.x & 7;       // XCD-pinned batch
    const int gl   = blockIdx.x >> 3;      // 0..63 within batch
    const int g0   = bb * 128 + gl * 2;    // first q-group
    const int m15  = lane & 15;

    const half8 qh0 = *(const half8*)(qfh + ((size_t)g0 * 64 + lane) * 8);
    const half8 ql0 = *(const half8*)(qfl + ((size_t)g0 * 64 + lane) * 8);
    const half8 qh1 = *(const half8*)(qfh + ((size_t)(g0 + 1) * 64 + lane) * 8);
    const half8 ql1 = *(const half8*)(qfl + ((size_t)(g0 + 1) * 64 + lane) * 8);

    const half8* KH = (const half8*)kfh + (size_t)bb * 128 * 64;
    const half8* KL = (const half8*)kfl + (size_t)bb * 128 * 64;
    const half4_t* VT = (const half4_t*)vtf + (size_t)bb * 128 * 64;

    const int nv = nvalid[bb];
    const int nt = (nv + 15) >> 4;         // 16-key tiles (<=128)
    const int a16 = (lane ^ 16) << 2;
    const int a32 = (lane ^ 32) << 2;

    float m0 = -INFINITY, m1 = -INFINITY;
    floatx4 o0 = {0.f, 0.f, 0.f, 0.f};
    floatx4 o1 = o0;

    int t = w;
    half8 kh, kl;
    half4_t va;
    if (t < nt) {
        kh = KH[t * 64 + lane];
        kl = KL[t * 64 + lane];
        va = VT[t * 64 + lane];
    }
    for (; t < nt; t += 4) {
        half8 nkh, nkl; half4_t nva;
        if (t + 4 < nt) {
            nkh = KH[(t + 4) * 64 + lane];
            nkl = KL[(t + 4) * 64 + lane];
            nva = VT[(t + 4) * 64 + lane];
        }
        floatx4 s0 = {0.f, 0.f, 0.f, 0.f};
        floatx4 s1 = s0;
        s0 = MFMA32F16(kh, qh0, s0);
        s1 = MFMA32F16(kh, qh1, s1);
        s0 = MFMA32F16(kl, qh0, s0);
        s1 = MFMA32F16(kl, qh1, s1);
        s0 = MFMA32F16(kh, ql0, s0);
        s1 = MFMA32F16(kh, ql1, s1);
        // group 0 softmax step
        {
            float pm = fmaxf(fmaxf(s0.x, s0.y), fmaxf(s0.z, s0.w));
            pm = fmaxf(pm, bperm(pm, a16));
            pm = fmaxf(pm, bperm(pm, a32));
            float mnew = fmaxf(m0, pm);
            float corr = EXP2F(m0 - mnew);
            o0.x *= corr; o0.y *= corr; o0.z *= corr; o0.w *= corr;
            half4_t pb;
            pb[0] = (_Float16)EXP2F(s0.x - mnew);
            pb[1] = (_Float16)EXP2F(s0.y - mnew);
            pb[2] = (_Float16)EXP2F(s0.z - mnew);
            pb[3] = (_Float16)EXP2F(s0.w - mnew);
            o0 = MFMA16F16(va, pb, o0);
            m0 = mnew;
        }
        // group 1 softmax step
        {
            float pm = fmaxf(fmaxf(s1.x, s1.y), fmaxf(s1.z, s1.w));
            pm = fmaxf(pm, bperm(pm, a16));
            pm = fmaxf(pm, bperm(pm, a32));
            float mnew = fmaxf(m1, pm);
            float corr = EXP2F(m1 - mnew);
            o1.x *= corr; o1.y *= corr; o1.z *= corr; o1.w *= corr;
            half4_t pb;
            pb[0] = (_Float16)EXP2F(s1.x - mnew);
            pb[1] = (_Float16)EXP2F(s1.y - mnew);
            pb[2] = (_Float16)EXP2F(s1.z - mnew);
            pb[3] = (_Float16)EXP2F(s1.w - mnew);
            o1 = MFMA16F16(va, pb, o1);
            m1 = mnew;
        }
        kh = nkh; kl = nkl; va = nva;
    }

    // ---- 4-way combine per group ----
    cm[(0 * 4 + w) * 64 + lane] = m0;
    cm[(1 * 4 + w) * 64 + lane] = m1;
    co[(0 * 4 + w) * 64 + lane] = o0;
    co[(1 * 4 + w) * 64 + lane] = o1;
    __syncthreads();
    if (w < 2) {
        const int gi = w;
        float gm = -INFINITY;
        #pragma unroll
        for (int w2 = 0; w2 < 4; ++w2) gm = fmaxf(gm, cm[(gi * 4 + w2) * 64 + lane]);
        floatx4 O = {0.f, 0.f, 0.f, 0.f};
        #pragma unroll
        for (int w2 = 0; w2 < 4; ++w2) {
            float f = EXP2F(cm[(gi * 4 + w2) * 64 + lane] - gm);
            floatx4 ow = co[(gi * 4 + w2) * 64 + lane];
            O.x += ow.x * f; O.y += ow.y * f; O.z += ow.z * f; O.w += ow.w * f;
        }
        float L = bperm(O.x, (48 + m15) << 2);   // l at C row 12
        float inv = 1.0f / L;
        if ((lane >> 4) < 3) {
            float4 ov = make_float4(O.x * inv, O.y * inv, O.z * inv, O.w * inv);
            *(float4*)(out + ((size_t)(g0 + gi) * 16 + m15) * 12 + (lane >> 4) * 4) = ov;
        }
    }
}

extern "C" void kernel_launch(void* const* d_in, const int* in_sizes, int n_in,
                              void* d_out, int out_size, void* d_ws, size_t ws_size,
                              hipStream_t stream) {
    const float* x    = (const float*)d_in[0];
    const int*   mask = (const int*)  d_in[1];
    const float* Wk   = (const float*)d_in[2];   // key_weight
    const float* Wq   = (const float*)d_in[3];   // query_weight
    const float* Wv   = (const float*)d_in[4];   // value_weight
    float* out = (float*)d_out;

    char* base = (char*)d_ws;
    _Float16* qfh = (_Float16*)(base);                    // 1 MB
    _Float16* qfl = (_Float16*)(base + (1u << 20));       // 1 MB
    _Float16* kfh = (_Float16*)(base + (2u << 20));       // 1 MB
    _Float16* kfl = (_Float16*)(base + (3u << 20));       // 1 MB
    _Float16* vtf = (_Float16*)(base + (4u << 20));       // 0.5 MB
    _Float16* wfh = (_Float16*)(base + 4718592);          // 73728 B
    _Float16* wfl = (_Float16*)(base + 4718592 + 73728);  // 73728 B
    int* dst      = (int*)(base + 4866048);               // 64 KB
    int* nvalid   = (int*)(base + 4866048 + 65536);       // 32 B
    float4* zbase = (float4*)(base + (2u << 20));         // zero [2MB, 4.5MB)

    prep<<<32, 256, 0, stream>>>(Wq, Wk, Wv, mask, wfh, wfl, dst, nvalid, zbase);
    qkv_mfma<<<1024, 256, 0, stream>>>(x, wfh, wfl, dst, qfh, qfl, kfh, kfl, vtf);
    attn<<<512, 256, 0, stream>>>(qfh, qfl, kfh, kfl, vtf, nvalid, out);
}